// Round 1
// baseline (270.737 us; speedup 1.0000x reference)
//
#include <hip/hip_runtime.h>
#include <stdint.h>

typedef unsigned long long u64;
typedef unsigned int u32;
typedef float fv4 __attribute__((ext_vector_type(4)));

// Problem constants (fixed by reference setup_inputs)
#define BATCH  8
#define NPTS   65536
#define NCLS   80
#define NANCH  (BATCH * NPTS)          // 524288
#define TOPK   4096
#define CONF   4.0f
#define NMSTH  0.5f
#define NCAT   (BATCH * NCLS)          // 640
#define BCAP   32                      // bucket capacity (Poisson lambda~2.1; P(>=32) ~ 1e-25)

// ws layout (bytes)
static constexpr size_t OFF_CNT  = 0;     // int cnt (64B pad)
static constexpr size_t OFF_KEYS = 64;    // u64 keys_raw[8192]

// ---------------- Kernel 1: per-anchor max/argmax + confidence compaction ----
// One 64-anchor chunk per wave, 4 independent waves per 256-thread block.
// Rationale vs the previous 2-chunk-per-wave version: A[20]+B[20] kept 160
// VGPRs of data live (=> ~200+ VGPR alloc, 2 waves/SIMD, spill risk). A single
// chunk (80 VGPRs data, ~110 total; __launch_bounds__(256,4) caps at 128)
// doubles occupancy to 4 waves/SIMD — same in-flight bytes per CU
// (16 waves x 20KB = 320KB), latency hiding by TLP instead of per-wave ILP.
// Per-wave: 20 nontemporal float4 loads (coalesced, 1KB/inst), LDS transpose
// with split arrays (u32 sortable score stride-21 conflict-free + u8 in-slot
// class) into this wave's private slice (wave-synchronous: in-order LDS pipe,
// no barriers), then each lane reduces its anchor's 20 slots; first slot
// attaining the max holds the lowest class attaining the global max -> exact
// jnp.argmax tie semantics.
// key = sortable(score):32 | (~idx&0x7FFFF):19 | cls:7
//   descending == (score desc, idx asc); cls bits don't disturb (idx unique).
__global__ __launch_bounds__(256, 4) void k_score(const float* __restrict__ logits,
                                                  int* __restrict__ cnt,
                                                  u64* __restrict__ keys) {
    __shared__ u32 s_sc[4][64 * 21];
    __shared__ unsigned char s_cl[4][64 * 20];
    int lane = threadIdx.x & 63;
    int w = threadIdx.x >> 6;
    int chunk = blockIdx.x * 4 + w;
    const fv4* src = (const fv4*)logits + (size_t)chunk * 1280;

    fv4 A[20];
#pragma unroll
    for (int k = 0; k < 20; ++k) A[k] = __builtin_nontemporal_load(&src[k * 64 + lane]);

    u32* sc = s_sc[w];
    unsigned char* cl = s_cl[w];

    // per-float4 max/argmax -> LDS transpose (wave-synchronous: each wave
    // touches only its own slice; single-wave in-order LDS pipe, compiler
    // orders via lgkmcnt waits)
#pragma unroll
    for (int k = 0; k < 20; ++k) {
        fv4 v = A[k];
        int e = k * 64 + lane;
        float bv = v.x; int bc = 0;
        if (v.y > bv) { bv = v.y; bc = 1; }
        if (v.z > bv) { bv = v.z; bc = 2; }
        if (v.w > bv) { bv = v.w; bc = 3; }
        int a_l = e / 20, j = e % 20;
        u32 eb = __float_as_uint(bv);
        eb = (eb & 0x80000000u) ? ~eb : (eb | 0x80000000u);   // sortable encode
        sc[a_l * 21 + j] = eb;
        cl[a_l * 20 + j] = (unsigned char)(j * 4 + bc);
    }
    u32 best = 0; int bj = 0;
#pragma unroll
    for (int j = 0; j < 20; ++j) {
        u32 p = sc[lane * 21 + j];
        if (p > best) { best = p; bj = j; }   // strict > : first max slot wins
    }
    u32 orig = (best & 0x80000000u) ? (best & 0x7fffffffu) : ~best;
    if (__uint_as_float(orig) > CONF) {
        u32 cls = cl[lane * 20 + bj];
        u32 a = (u32)chunk * 64 + (u32)lane;
        int pos = atomicAdd(cnt, 1);
        if (pos < 8192)
            keys[pos] = ((u64)best << 32) | ((((~a) & 0x7FFFFu) << 7) | cls);
    }
}

// ---------------- Kernel 2: sort + decode + gather + per-category greedy NMS ----
// (unchanged this round — isolate the k_score delta)
// Bitonic sort fused in (next_pow2(n) elements, in-LDS). Then: suppression
// requires cat[i]==cat[j], so global greedy NMS == independent greedy per
// category. Bucket items by cat (640 buckets, ~2 items each), one thread per
// category replays the exact sequential greedy on its bucket.
__global__ __launch_bounds__(1024) void k_nms(const int* __restrict__ cnt,
                                              const u64* __restrict__ keys_raw,
                                              const float* __restrict__ boxes,
                                              float* __restrict__ out) {
    __shared__ u64    s_keys[4096];                   // 32 KB
    __shared__ float4 s_box[4096];                    // 64 KB
    __shared__ unsigned short s_bucket[NCAT * BCAP];  // 40 KB
    __shared__ int s_bcnt[NCAT];                      // 2.5 KB
    __shared__ unsigned char s_keep[4096];            // 4 KB
    int n = min(*cnt, TOPK);
    int tid = threadIdx.x;
    int n2 = 64; while (n2 < n) n2 <<= 1;

    for (int c = tid; c < NCAT; c += 1024) s_bcnt[c] = 0;
    for (int i = tid; i < n2; i += 1024)
        s_keys[i] = (i < n) ? keys_raw[i] : 0ull;   // sentinel 0 < any valid key (valid >= 2^63)
    __syncthreads();

    // bitonic, descending
    for (int k = 2; k <= n2; k <<= 1) {
        for (int j = k >> 1; j > 0; j >>= 1) {
            for (int i = tid; i < n2; i += 1024) {
                int ixj = i ^ j;
                if (ixj > i) {
                    u64 x = s_keys[i], y = s_keys[ixj];
                    bool desc = ((i & k) == 0);
                    if (desc ? (x < y) : (x > y)) { s_keys[i] = y; s_keys[ixj] = x; }
                }
            }
            __syncthreads();
        }
    }

    // decode + gather boxes + fill category buckets
    float4 bx[4]; int cls_[4], img_[4]; float sc_[4];
#pragma unroll
    for (int r = 0; r < 4; ++r) {
        int s = tid + 1024 * r;
        float4 b = make_float4(0.f, 0.f, 0.f, 0.f);
        int cl = -1, im = -1; float v = 0.f;
        if (s < n) {
            u64 key = s_keys[s];
            u32 eb = (u32)(key >> 32);
            u32 orig = (eb & 0x80000000u) ? (eb & 0x7fffffffu) : ~eb;
            v = __uint_as_float(orig);
            u32 low = (u32)key;
            cl = (int)(low & 0x7fu);
            u32 a = (~(low >> 7)) & 0x7FFFFu;
            im = (int)(a >> 16);                      // a / NPTS
            b = ((const float4*)boxes)[a];
            int c = im * NCLS + cl;
            int pos = atomicAdd(&s_bcnt[c], 1);
            if (pos < BCAP) s_bucket[c * BCAP + pos] = (unsigned short)s;
        }
        bx[r] = b; cls_[r] = cl; img_[r] = im; sc_[r] = v;
        s_box[s]  = b;
        s_keep[s] = (s < n) ? 1 : 0;
    }
    __syncthreads();

    // per-category exact greedy (disjoint buckets -> no cross-thread races)
    if (tid < NCAT) {
        int m = min(s_bcnt[tid], BCAP);
        unsigned short* bkt = &s_bucket[tid * BCAP];
        if (m > 1) {
            // insertion sort ascending by rank s (rank order within category)
            for (int i = 1; i < m; ++i) {
                unsigned short x = bkt[i]; int j = i - 1;
                while (j >= 0 && bkt[j] > x) { bkt[j + 1] = bkt[j]; --j; }
                bkt[j + 1] = x;
            }
            for (int i = 1; i < m; ++i) {
                float4 bi = s_box[bkt[i]];
                float areai = (bi.z - bi.x) * (bi.w - bi.y);
                bool dead = false;
                for (int j = 0; j < i && !dead; ++j) {
                    if (!s_keep[bkt[j]]) continue;    // only kept items suppress
                    float4 bj = s_box[bkt[j]];
                    float iw = fmaxf(fminf(bi.z, bj.z) - fmaxf(bi.x, bj.x), 0.f);
                    float ih = fmaxf(fminf(bi.w, bj.w) - fmaxf(bi.y, bj.y), 0.f);
                    float inter = iw * ih;
                    float uni = areai + (bj.z - bj.x) * (bj.w - bj.y) - inter;
                    if (inter / fmaxf(uni, 1e-12f) > NMSTH) dead = true;
                }
                if (dead) s_keep[bkt[i]] = 0;
            }
        }
    }
    __syncthreads();

    // outputs: [img 4096][boxes 16384][cls 4096][score 4096], all float32
#pragma unroll
    for (int r = 0; r < 4; ++r) {
        int s = tid + 1024 * r;
        bool keep = s_keep[s] != 0;
        out[s] = keep ? (float)img_[r] : -1.0f;
        ((float4*)(out + 4096))[s] = keep ? bx[r] : make_float4(0.f, 0.f, 0.f, 0.f);
        out[4096 + 16384 + s]        = keep ? (float)cls_[r] : -1.0f;
        out[4096 + 16384 + 4096 + s] = keep ? sc_[r] : 0.0f;
    }
}

extern "C" void kernel_launch(void* const* d_in, const int* in_sizes, int n_in,
                              void* d_out, int out_size, void* d_ws, size_t ws_size,
                              hipStream_t stream) {
    const float* logits = (const float*)d_in[0];
    const float* boxes  = (const float*)d_in[1];
    float* out = (float*)d_out;
    char* ws = (char*)d_ws;

    int* cnt      = (int*)(ws + OFF_CNT);
    u64* keys_raw = (u64*)(ws + OFF_KEYS);

    hipMemsetAsync(cnt, 0, 64, stream);
    k_score<<<NANCH / 256, 256, 0, stream>>>(logits, cnt, keys_raw);
    k_nms<<<1, 1024, 0, stream>>>(cnt, keys_raw, boxes, out);
}